// Round 3
// baseline (569.419 us; speedup 1.0000x reference)
//
#include <hip/hip_runtime.h>
#include <hip/hip_cooperative_groups.h>
#include <math.h>

namespace cg = cooperative_groups;

#define B_   128
#define R_   1152
#define C_   16
#define O_   16
#define RS_  32            // split-K chunks for s-phase
#define RCH_ 36            // R_/RS_

// ws layout (floats): blog[18432] | cw[18432] | v[32768] | sp[RS_*32768 = 1048576]
#define WS_BLOG 0
#define WS_CW   18432
#define WS_V    36864
#define WS_SP   69632

__global__ __launch_bounds__(512, 2) void caps_k(const float* __restrict__ x,
                                                 const float* __restrict__ W,
                                                 float* __restrict__ out,
                                                 float* __restrict__ ws) {
    cg::grid_group grid = cg::this_grid();
    const int t   = threadIdx.x;
    const int blk = blockIdx.x;

    float* blog = ws + WS_BLOG;
    float* cw   = ws + WS_CW;
    float* vbuf = ws + WS_V;
    float* sp   = ws + WS_SP;

    const float4* __restrict__ X4 = (const float4*)x;
    const float4* __restrict__ W4 = (const float4*)W;

    __shared__ float smem[8192];          // 32 KB, reused per phase
    float4* xl4 = (float4*)smem;

    for (int it = 0; it < 3; ++it) {
        // ---------------- P1: softmax over r (axis 0) per column c ----------
        if (it > 0) {
            if (blk < C_) {
                const int c = blk;
                float m = -1e30f;
                for (int r = t; r < R_; r += 512) m = fmaxf(m, blog[r * C_ + c]);
                smem[t] = m; __syncthreads();
                for (int s2 = 256; s2 > 0; s2 >>= 1) {
                    if (t < s2) smem[t] = fmaxf(smem[t], smem[t + s2]);
                    __syncthreads();
                }
                const float M = smem[0]; __syncthreads();
                float e = 0.f;
                for (int r = t; r < R_; r += 512) e += __expf(blog[r * C_ + c] - M);
                smem[t] = e; __syncthreads();
                for (int s2 = 256; s2 > 0; s2 >>= 1) {
                    if (t < s2) smem[t] += smem[t + s2];
                    __syncthreads();
                }
                const float inv = 1.0f / smem[0];
                __syncthreads();
                for (int r = t; r < R_; r += 512)
                    cw[r * C_ + c] = __expf(blog[r * C_ + c] - M) * inv;
            }
            grid.sync();
        }

        // ---------------- P2: s partials (split-K GEMM) ---------------------
        // block = (bt = blk>>5 in 0..7, rs = blk&31). thread: co4 = t&63, b8 = t>>6.
        {
            const int bt  = blk >> 5;
            const int rs  = blk & 31;
            const int co4 = t & 63;
            const int b8  = t >> 6;
            const int c   = co4 >> 2;
            const int r0  = rs * RCH_;

            // stage x[bt*16 + bl][r0 .. r0+35][0:8]  (1152 float4)
            #pragma unroll
            for (int k = 0; k < 3; ++k) {
                const int u = t + k * 512;
                if (u < 1152) {
                    const int bl = u / 72, rem = u % 72;
                    xl4[u] = X4[((bt * 16 + bl) * R_ + r0) * 2 + rem];
                }
            }
            __syncthreads();

            float acc[2][4] = {{0.f, 0.f, 0.f, 0.f}, {0.f, 0.f, 0.f, 0.f}};
            #pragma unroll 4
            for (int rr = 0; rr < RCH_; ++rr) {
                const int r = r0 + rr;
                const float cwv = (it == 0) ? (1.0f / (float)R_) : cw[r * C_ + c];
                const int wb = r * 512 + co4 * 8;
                const float4 w0 = W4[wb + 0], w1 = W4[wb + 1], w2 = W4[wb + 2], w3 = W4[wb + 3];
                const float4 w4 = W4[wb + 4], w5 = W4[wb + 5], w6 = W4[wb + 6], w7 = W4[wb + 7];
                #pragma unroll
                for (int j = 0; j < 2; ++j) {
                    const int bl = b8 * 2 + j;
                    const float4 xa = xl4[bl * 72 + rr * 2];
                    const float4 xb = xl4[bl * 72 + rr * 2 + 1];
                    const float d0 = w0.x*xa.x + w0.y*xa.y + w0.z*xa.z + w0.w*xa.w
                                   + w1.x*xb.x + w1.y*xb.y + w1.z*xb.z + w1.w*xb.w;
                    const float d1 = w2.x*xa.x + w2.y*xa.y + w2.z*xa.z + w2.w*xa.w
                                   + w3.x*xb.x + w3.y*xb.y + w3.z*xb.z + w3.w*xb.w;
                    const float d2 = w4.x*xa.x + w4.y*xa.y + w4.z*xa.z + w4.w*xa.w
                                   + w5.x*xb.x + w5.y*xb.y + w5.z*xb.z + w5.w*xb.w;
                    const float d3 = w6.x*xa.x + w6.y*xa.y + w6.z*xa.z + w6.w*xa.w
                                   + w7.x*xb.x + w7.y*xb.y + w7.z*xb.z + w7.w*xb.w;
                    acc[j][0] = fmaf(cwv, d0, acc[j][0]);
                    acc[j][1] = fmaf(cwv, d1, acc[j][1]);
                    acc[j][2] = fmaf(cwv, d2, acc[j][2]);
                    acc[j][3] = fmaf(cwv, d3, acc[j][3]);
                }
            }

            float4* sp4 = (float4*)sp;
            #pragma unroll
            for (int j = 0; j < 2; ++j) {
                const int b = bt * 16 + b8 * 2 + j;
                float4 o4; o4.x = acc[j][0]; o4.y = acc[j][1]; o4.z = acc[j][2]; o4.w = acc[j][3];
                sp4[(rs * B_ + b) * 64 + co4] = o4;
            }
        }
        grid.sync();

        // ---------------- P3: reduce split-K + squash -----------------------
        {
            float* vout = (it == 2) ? out : vbuf;
            if (blk < 64) {
                const int idx = blk * 512 + t;        // 0..32767
                float s = 0.f;
                #pragma unroll
                for (int k = 0; k < RS_; ++k) s += sp[k * (B_ * 256) + idx];
                vout[idx] = s * fabsf(s) / (1.0f + s * s);
            }
            if (it == 2) return;                       // final output written; done
        }
        grid.sync();

        // ---------------- P4: a-update, blog[r,c] (+)= mean_b<u_hat, v> -----
        // 144 blocks x 8 waves: wave w handles r = blk*8 + w via Y = x^T v.
        if (blk < 144) {
            const int r0   = blk * 8;
            const int w    = t >> 6;
            const int co4  = t & 63;
            const int c    = co4 >> 2;
            const int r    = r0 + w;
            const float4* __restrict__ V4 = (const float4*)vbuf;

            __syncthreads();   // smem reuse safety within block (P2 used it)
            // stage x[b][r0..r0+7][0:8]  (2048 float4 = 32 KB)
            #pragma unroll
            for (int k = 0; k < 4; ++k) {
                const int u = t + k * 512;            // 0..2047
                const int b = u >> 4, rem = u & 15;
                xl4[u] = X4[(b * R_ + r0) * 2 + rem];
            }
            __syncthreads();

            float y[8][4];
            #pragma unroll
            for (int i = 0; i < 8; ++i)
                #pragma unroll
                for (int q = 0; q < 4; ++q) y[i][q] = 0.f;

            #pragma unroll 4
            for (int b = 0; b < B_; ++b) {
                const float4 xa = xl4[b * 16 + w * 2];
                const float4 xb = xl4[b * 16 + w * 2 + 1];
                const float4 vv = V4[b * 64 + co4];
                const float xs[8] = {xa.x, xa.y, xa.z, xa.w, xb.x, xb.y, xb.z, xb.w};
                #pragma unroll
                for (int i = 0; i < 8; ++i) {
                    y[i][0] = fmaf(xs[i], vv.x, y[i][0]);
                    y[i][1] = fmaf(xs[i], vv.y, y[i][1]);
                    y[i][2] = fmaf(xs[i], vv.z, y[i][2]);
                    y[i][3] = fmaf(xs[i], vv.w, y[i][3]);
                }
            }

            // contract with W[r]: part = sum_{q,i} W[r, co4*4+q, i] * y[i][q]
            const int wb = r * 512 + co4 * 8;
            float part = 0.f;
            #pragma unroll
            for (int q = 0; q < 4; ++q) {
                const float4 w0 = W4[wb + q * 2];
                const float4 w1 = W4[wb + q * 2 + 1];
                part += w0.x*y[0][q] + w0.y*y[1][q] + w0.z*y[2][q] + w0.w*y[3][q]
                      + w1.x*y[4][q] + w1.y*y[5][q] + w1.z*y[6][q] + w1.w*y[7][q];
            }
            part += __shfl_xor(part, 1);
            part += __shfl_xor(part, 2);
            if ((co4 & 3) == 0) {
                const float a = part * (1.0f / (float)B_);
                if (it == 0) blog[r * C_ + c] = a;        // blog starts undefined (ws poison)
                else         blog[r * C_ + c] += a;
            }
        }
        grid.sync();
    }
}

extern "C" void kernel_launch(void* const* d_in, const int* in_sizes, int n_in,
                              void* d_out, int out_size, void* d_ws, size_t ws_size,
                              hipStream_t stream) {
    const float* x = (const float*)d_in[0];   // [128,1152,8]
    const float* W = (const float*)d_in[1];   // [1,1152,16,16,8]
    float* out = (float*)d_out;               // [128,16,16]
    float* ws  = (float*)d_ws;                // needs ~4.5 MB

    void* args[] = { (void*)&x, (void*)&W, (void*)&out, (void*)&ws };
    hipLaunchCooperativeKernel((void*)caps_k, dim3(256), dim3(512), args, 0, stream);
}

// Round 4
// 247.153 us; speedup vs baseline: 2.3039x; 2.3039x over previous
//
#include <hip/hip_runtime.h>
#include <math.h>

#define B_   128
#define R_   1152
#define C_   16
#define O_   16
#define RS_  64
#define RCH_ 18            // R_/RS_

// ws layout (floats)
#define WS_BLOG 0           // 18432
#define WS_CW   18432       // 18432
#define WS_V    36864       // 32768
#define WS_AB   69632       // 2*18432
#define WS_SP   106496      // RS_*32768

// ---------------- fused blog-accumulate + softmax over r (axis 0) ----------------
// grid C_ x 256. blog[r,c] (+)= (ab0+ab1)/B, then cw[:,c] = softmax(blog[:,c]).
__global__ void softmax_k(float* __restrict__ blog, const float* __restrict__ ab,
                          float* __restrict__ cw, int first) {
    const int c = blockIdx.x;
    const int t = threadIdx.x;
    __shared__ float red[256];

    float m = -1e30f;
    for (int r = t; r < R_; r += 256) {
        const float prev = first ? 0.f : blog[r * C_ + c];
        const float bl = prev + (ab[r * C_ + c] + ab[R_ * C_ + r * C_ + c]) * (1.0f / (float)B_);
        blog[r * C_ + c] = bl;
        m = fmaxf(m, bl);
    }
    red[t] = m; __syncthreads();
    for (int s = 128; s > 0; s >>= 1) {
        if (t < s) red[t] = fmaxf(red[t], red[t + s]);
        __syncthreads();
    }
    const float M = red[0]; __syncthreads();

    float e = 0.f;
    for (int r = t; r < R_; r += 256) e += __expf(blog[r * C_ + c] - M);
    red[t] = e; __syncthreads();
    for (int s = 128; s > 0; s >>= 1) {
        if (t < s) red[t] += red[t + s];
        __syncthreads();
    }
    const float inv = 1.0f / red[0];

    for (int r = t; r < R_; r += 256)
        cw[r * C_ + c] = __expf(blog[r * C_ + c] - M) * inv;
}

// ---------------- GEMM1: sp[rs][b][co] = sum_{r in chunk, i} x[b,r,i]*cw[r,c]*W[r,co,i]
// grid (8 bt, RS_ rs) x 256 thr. Thread: co4 = t&63 (4 co), b4 = t>>6 (4 b).
// 2048 waves = 2/SIMD. UNIFORM: iter-0 softmax == 1/R exactly.
template <bool UNIFORM>
__global__ __launch_bounds__(256) void gemm1_k(const float* __restrict__ x,
                                               const float* __restrict__ W,
                                               const float* __restrict__ cw,
                                               float* __restrict__ sp) {
    const int bt  = blockIdx.x;
    const int rs  = blockIdx.y;
    const int t   = threadIdx.x;
    const int co4 = t & 63;
    const int b4  = t >> 6;
    const int c   = co4 >> 2;
    const int r0  = rs * RCH_;

    __shared__ float4 xl4[16 * 2 * RCH_];   // 16 b x 18 r x 32B = 9 KB
    const float4* __restrict__ X4 = (const float4*)x;
    const float4* __restrict__ W4 = (const float4*)W;

    // stage x[bt*16 + bl][r0..r0+17][0:8] -> 576 float4
    {
        int u = t;
        {
            const int bl = u / 36, rem = u % 36;
            xl4[u] = X4[((bt * 16 + bl) * R_ + r0) * 2 + rem];
        }
        u = t + 256;
        {
            const int bl = u / 36, rem = u % 36;
            xl4[u] = X4[((bt * 16 + bl) * R_ + r0) * 2 + rem];
        }
        u = t + 512;
        if (u < 576) {
            const int bl = u / 36, rem = u % 36;
            xl4[u] = X4[((bt * 16 + bl) * R_ + r0) * 2 + rem];
        }
    }
    __syncthreads();

    float acc[4][4];
    #pragma unroll
    for (int j = 0; j < 4; ++j)
        #pragma unroll
        for (int q = 0; q < 4; ++q) acc[j][q] = 0.f;

    #pragma unroll 2
    for (int rr = 0; rr < RCH_; ++rr) {
        const int r = r0 + rr;
        const float cwv = UNIFORM ? (1.0f / (float)R_) : cw[r * C_ + c];
        const int wb = r * 512 + co4 * 8;
        const float4 w0 = W4[wb + 0], w1 = W4[wb + 1], w2 = W4[wb + 2], w3 = W4[wb + 3];
        const float4 w4 = W4[wb + 4], w5 = W4[wb + 5], w6 = W4[wb + 6], w7 = W4[wb + 7];
        #pragma unroll
        for (int j = 0; j < 4; ++j) {
            const float4 xa = xl4[(b4 * 4 + j) * 36 + rr * 2];
            const float4 xb = xl4[(b4 * 4 + j) * 36 + rr * 2 + 1];
            const float d0 = w0.x*xa.x + w0.y*xa.y + w0.z*xa.z + w0.w*xa.w
                           + w1.x*xb.x + w1.y*xb.y + w1.z*xb.z + w1.w*xb.w;
            const float d1 = w2.x*xa.x + w2.y*xa.y + w2.z*xa.z + w2.w*xa.w
                           + w3.x*xb.x + w3.y*xb.y + w3.z*xb.z + w3.w*xb.w;
            const float d2 = w4.x*xa.x + w4.y*xa.y + w4.z*xa.z + w4.w*xa.w
                           + w5.x*xb.x + w5.y*xb.y + w5.z*xb.z + w5.w*xb.w;
            const float d3 = w6.x*xa.x + w6.y*xa.y + w6.z*xa.z + w6.w*xa.w
                           + w7.x*xb.x + w7.y*xb.y + w7.z*xb.z + w7.w*xb.w;
            acc[j][0] = fmaf(cwv, d0, acc[j][0]);
            acc[j][1] = fmaf(cwv, d1, acc[j][1]);
            acc[j][2] = fmaf(cwv, d2, acc[j][2]);
            acc[j][3] = fmaf(cwv, d3, acc[j][3]);
        }
    }

    float4* sp4 = (float4*)sp;
    #pragma unroll
    for (int j = 0; j < 4; ++j) {
        const int b = bt * 16 + b4 * 4 + j;
        float4 o4; o4.x = acc[j][0]; o4.y = acc[j][1]; o4.z = acc[j][2]; o4.w = acc[j][3];
        sp4[(rs * B_ + b) * 64 + co4] = o4;
    }
}

// ---------------- reduce split-K partials + squash: v = s*|s|/(1+s^2) ----------------
__global__ void reduce_squash_k(const float* __restrict__ sp, float* __restrict__ v) {
    const int idx = blockIdx.x * 256 + threadIdx.x;   // 0..32767
    float s = 0.f;
    #pragma unroll 8
    for (int k = 0; k < RS_; ++k) s += sp[k * (B_ * 256) + idx];
    v[idx] = s * fabsf(s) / (1.0f + s * s);
}

// ---------------- a partials via Y = x^T v: ab[half][r][c] ----------------
// grid 288 x 512. Wave w of 8: r = blk*4 + (w&3), half = w>>2 (64 b's each).
// 2304 waves = 2.25/SIMD. Lane co4 holds Y[r][0:8][co4*4..+3] in 32 regs.
__global__ __launch_bounds__(512) void a_part_k(const float* __restrict__ x,
                                                const float* __restrict__ W,
                                                const float* __restrict__ v,
                                                float* __restrict__ ab) {
    const int r0   = blockIdx.x * 4;
    const int t    = threadIdx.x;
    const int w    = t >> 6;
    const int rr   = w & 3;
    const int half = w >> 2;
    const int co4  = t & 63;
    const int c    = co4 >> 2;
    const int r    = r0 + rr;

    __shared__ float4 xl4[128 * 8];      // x[b][r0..r0+3][0:8] = 16 KB
    const float4* __restrict__ X4 = (const float4*)x;
    const float4* __restrict__ V4 = (const float4*)v;
    const float4* __restrict__ W4 = (const float4*)W;

    #pragma unroll
    for (int k = 0; k < 2; ++k) {
        const int u = t + k * 512;       // 0..1023
        const int b = u >> 3, rem = u & 7;
        xl4[u] = X4[(b * R_ + r0) * 2 + rem];
    }
    __syncthreads();

    float y[8][4];
    #pragma unroll
    for (int i = 0; i < 8; ++i)
        #pragma unroll
        for (int q = 0; q < 4; ++q) y[i][q] = 0.f;

    const int b0 = half * 64;
    #pragma unroll 4
    for (int bb = 0; bb < 64; ++bb) {
        const int b = b0 + bb;
        const float4 xa = xl4[b * 8 + rr * 2];
        const float4 xb = xl4[b * 8 + rr * 2 + 1];
        const float4 vv = V4[b * 64 + co4];
        const float xs[8] = {xa.x, xa.y, xa.z, xa.w, xb.x, xb.y, xb.z, xb.w};
        #pragma unroll
        for (int i = 0; i < 8; ++i) {
            y[i][0] = fmaf(xs[i], vv.x, y[i][0]);
            y[i][1] = fmaf(xs[i], vv.y, y[i][1]);
            y[i][2] = fmaf(xs[i], vv.z, y[i][2]);
            y[i][3] = fmaf(xs[i], vv.w, y[i][3]);
        }
    }

    // contract with W[r]: part = sum_{q,i} W[r, co4*4+q, i] * y[i][q]
    const int wb = r * 512 + co4 * 8;
    float part = 0.f;
    #pragma unroll
    for (int q = 0; q < 4; ++q) {
        const float4 w0 = W4[wb + q * 2];
        const float4 w1 = W4[wb + q * 2 + 1];
        part += w0.x*y[0][q] + w0.y*y[1][q] + w0.z*y[2][q] + w0.w*y[3][q]
              + w1.x*y[4][q] + w1.y*y[5][q] + w1.z*y[6][q] + w1.w*y[7][q];
    }
    part += __shfl_xor(part, 1);
    part += __shfl_xor(part, 2);
    if ((co4 & 3) == 0) ab[half * (R_ * C_) + r * C_ + c] = part;
}

extern "C" void kernel_launch(void* const* d_in, const int* in_sizes, int n_in,
                              void* d_out, int out_size, void* d_ws, size_t ws_size,
                              hipStream_t stream) {
    const float* x = (const float*)d_in[0];   // [128,1152,8]
    const float* W = (const float*)d_in[1];   // [1,1152,16,16,8]
    float* out = (float*)d_out;               // [128,16,16]
    float* ws  = (float*)d_ws;                // ~8.8 MB used

    float* blog = ws + WS_BLOG;
    float* cw   = ws + WS_CW;
    float* vbuf = ws + WS_V;
    float* ab   = ws + WS_AB;
    float* sp   = ws + WS_SP;

    // it 0: softmax(0) == 1/R exactly
    gemm1_k<true><<<dim3(8, RS_), 256, 0, stream>>>(x, W, cw, sp);
    reduce_squash_k<<<128, 256, 0, stream>>>(sp, vbuf);
    a_part_k<<<288, 512, 0, stream>>>(x, W, vbuf, ab);

    // it 1
    softmax_k<<<C_, 256, 0, stream>>>(blog, ab, cw, 1);
    gemm1_k<false><<<dim3(8, RS_), 256, 0, stream>>>(x, W, cw, sp);
    reduce_squash_k<<<128, 256, 0, stream>>>(sp, vbuf);
    a_part_k<<<288, 512, 0, stream>>>(x, W, vbuf, ab);

    // it 2
    softmax_k<<<C_, 256, 0, stream>>>(blog, ab, cw, 0);
    gemm1_k<false><<<dim3(8, RS_), 256, 0, stream>>>(x, W, cw, sp);
    reduce_squash_k<<<128, 256, 0, stream>>>(sp, out);
}